// Round 18
// baseline (228.892 us; speedup 1.0000x reference)
//
#include <hip/hip_runtime.h>
#include <hip/hip_bf16.h>
#include <math.h>

// ---------------------------------------------------------------------------
// FeatureNet (DGCNN edge-conv block), MI355X / gfx950, round 18.
//
// Round-18 changes (base = r17 proven, 153.5us):
//  * kNN: 2 points per wave (Pass A candidate reads amortized 2x; the proven
//    bound/compact/bitonic/gather pipeline runs twice per wave, wave-private).
//  * finalize2/finalize3 folded into conv3 / bn3max prologues (per-block
//    affine from banked stats, exact same f64 math). 7 -> 5 launches.
// ---------------------------------------------------------------------------

#define B_   16
#define N_   2048
#define KNN  8
#define DIM  128
#define P_   (B_*N_*KNN)   // 262144
#define CAP  128
#define NBLK 2048          // conv blocks (128 p each)
#define KBLKS 1024         // knn blocks (32 points each)

typedef __attribute__((ext_vector_type(8))) short bf16x8;
typedef __attribute__((ext_vector_type(4))) short bf16x4;
typedef __attribute__((ext_vector_type(4))) float f32x4;

// ws layout (bytes)
#define OFF_G     0ull
#define SZ_G      ((size_t)3*P_*4)
#define OFF_Y2B   (OFF_G + SZ_G)
#define SZ_Y2B    ((size_t)DIM*P_*2)           // 67,108,864  (y2t[p][c])
#define OFF_STATS (OFF_Y2B + SZ_Y2B)
#define N_STATS   4112
#define SZ_STATS  ((size_t)N_STATS*8)
#define OFF_AB    (OFF_STATS + SZ_STATS)
#define SZ_AB     4096ull
#define OFF_KPART (OFF_AB + SZ_AB)
#define SZ_KPART  ((size_t)9*2048*4)
#define OFF_YMM   (OFF_KPART + SZ_KPART)
#define SZ_YMM    ((size_t)DIM*NBLK*16*4)      // packed u32 (max,min)

// stats (f64) indices
#define I_S2   16
#define I_S3   (16 + 8*256)
#define NBANK  8

// ab (float) layout
#define AB_W1F 0

// DPP ctrl codes (all source lanes valid)
#define DPP_XOR1   0xB1    // quad_perm [1,0,3,2]
#define DPP_XOR2   0x4E    // quad_perm [2,3,0,1]
#define DPP_HALFM  0x141   // row_half_mirror: lane ^ 7
#define DPP_MIRROR 0x140   // row_mirror: lane ^ 15

template<int C>
__device__ __forceinline__ float dppf(float v) {
    return __int_as_float(__builtin_amdgcn_update_dpp(
        __float_as_int(v), __float_as_int(v), C, 0xF, 0xF, false));
}

__device__ __forceinline__ void atomAddD(double* p, double v) {
    __hip_atomic_fetch_add(p, v, __ATOMIC_RELAXED, __HIP_MEMORY_SCOPE_AGENT);
}
__device__ __forceinline__ unsigned short f2bs(float f) {
    const unsigned b = __float_as_uint(f);
    return (unsigned short)((b + 0x7FFFu + ((b >> 16) & 1u)) >> 16);   // RNE
}
__device__ __forceinline__ float bs2f(unsigned short u) {
    return __uint_as_float(((unsigned)u) << 16);
}

// ---------------------------------------------------------------------------
// Per-point exact top-8 selection (r16/r17-proven sub-pipeline).
// All 64 lanes of the wave must call. Returns neighbor idx for lane<8.
__device__ __forceinline__ int select8(
    const float (&dreg)[32], float lmin,
    unsigned long long* __restrict__ listKw, int ln)
{
    // bound B' = max over 8 groups of (min over each 8-lane group)
    float gm = lmin;
    gm = fminf(gm, __shfl_xor(gm, 1));
    gm = fminf(gm, __shfl_xor(gm, 2));
    gm = fminf(gm, __shfl_xor(gm, 4));
    float Bb = gm;
    Bb = fmaxf(Bb, __shfl_xor(Bb, 8));
    Bb = fmaxf(Bb, __shfl_xor(Bb, 16));
    Bb = fmaxf(Bb, __shfl_xor(Bb, 32));

    // ballot-compact packed keys (orderable(d)<<32 | idx)
    unsigned base = 0;
    #pragma unroll
    for (int i = 0; i < 32; ++i) {
        const bool pred = (dreg[i] <= Bb);
        const unsigned long long mk = __ballot(pred);
        if (pred) {
            const unsigned pos = base + (unsigned)__popcll(mk & ((1ull << ln) - 1ull));
            if (pos < CAP) {
                const unsigned u = __float_as_uint(dreg[i]);
                const unsigned od = u ^ ((unsigned)(((int)u) >> 31) | 0x80000000u);
                listKw[pos] = (((unsigned long long)od) << 32) | (unsigned)(ln + 64*i);
            }
        }
        base += (unsigned)__popcll(mk);
    }
    const int cnt = (base < CAP) ? (int)base : CAP;

    int myi = 0;
    if (cnt <= 64) {
        // 64-lane bitonic sort; lanes 0..7 end with ranks 0..7
        unsigned long long K = (ln < cnt) ? listKw[ln] : ~0ull;
        #pragma unroll
        for (int k = 2; k <= 64; k <<= 1) {
            #pragma unroll
            for (int j = k >> 1; j >= 1; j >>= 1) {
                const unsigned long long o = __shfl_xor(K, j);
                const bool takeMin = (((ln & j) == 0) == ((ln & k) == 0));
                const bool oLess = (o < K);
                if (takeMin ? oLess : !oLess) K = o;
            }
        }
        myi = (int)(unsigned)K;
    } else {
        unsigned long long K0 = (ln < cnt)      ? listKw[ln]      : ~0ull;
        unsigned long long K1 = (ln + 64 < cnt) ? listKw[ln + 64] : ~0ull;
        #pragma unroll
        for (int sel = 0; sel < 8; ++sel) {
            unsigned long long p = (K1 < K0) ? K1 : K0;
            #pragma unroll
            for (int m = 1; m < 64; m <<= 1) {
                const unsigned long long o = __shfl_xor(p, m);
                if (o < p) p = o;
            }
            if (ln == sel) myi = (int)(unsigned)p;
            if (K0 == p) K0 = ~0ull;
            if (K1 == p) K1 = ~0ull;
        }
    }
    return myi;
}

// ---------------------------------------------------------------------------
// kNN: block = 1024 thr = 16 waves = 32 points (2 per wave).
// Pass A reads each candidate ONCE per wave (serves both points).
__global__ __launch_bounds__(1024) void knn_group_kernel(
    const float* __restrict__ x, float* __restrict__ g,
    float* __restrict__ kpart, double* __restrict__ st)
{
    __shared__ __align__(16) float4 xs4[N_];           // 32 KB
    __shared__ unsigned long long listK[16][CAP];      // 16 KB
    __shared__ float spart[16][12];
    const int b   = blockIdx.y;
    const int tid = threadIdx.x;
    const int wv  = tid >> 6;
    const int ln  = tid & 63;
    const int nA  = blockIdx.x * 32 + 2*wv;
    const int nB  = nA + 1;
    const float* xb = x + (size_t)b * 3 * N_;

    if (blockIdx.x == 0 && blockIdx.y == 0)
        for (int i = tid; i < N_STATS; i += 1024) st[i] = 0.0;

    for (int i = tid; i < N_; i += 1024) {
        const float a0 = xb[i], a1 = xb[N_ + i], a2 = xb[2*N_ + i];
        const float sq = __fadd_rn(__fadd_rn(__fmul_rn(a0,a0), __fmul_rn(a1,a1)), __fmul_rn(a2,a2));
        xs4[i] = make_float4(a0, a1, a2, sq);
    }
    __syncthreads();

    const float4 meA = xs4[nA];
    const float4 meB = xs4[nB];

    // ---- Pass A: shared candidate reads, distances for BOTH points
    float dA[32], dB[32];
    float lminA = INFINITY, lminB = INFINITY;
    #pragma unroll
    for (int i = 0; i < 32; ++i) {
        const float4 q = xs4[ln + 64*i];
        dA[i] = __fadd_rn(__fmaf_rn(-2.f,
                    __fmaf_rn(meA.z, q.z, __fmaf_rn(meA.y, q.y, __fmul_rn(meA.x, q.x))),
                    meA.w), q.w);
        dB[i] = __fadd_rn(__fmaf_rn(-2.f,
                    __fmaf_rn(meB.z, q.z, __fmaf_rn(meB.y, q.y, __fmul_rn(meB.x, q.x))),
                    meB.w), q.w);
        lminA = fminf(lminA, dA[i]);
        lminB = fminf(lminB, dB[i]);
    }

    float s0=0.f,s1=0.f,s2=0.f,s00=0.f,s01=0.f,s02=0.f,s11=0.f,s12=0.f,s22=0.f;

    // ---- point A
    {
        const int myi = select8(dA, lminA, listK[wv], ln);
        if (ln < 8) {
            const float4 q = xs4[myi];
            const float g0  = q.x - meA.x;
            const float g1v = q.y - meA.y;
            const float g2v = q.z - meA.z;
            const size_t basep = ((size_t)b*N_ + nA) * KNN;
            g[0*P_ + basep + ln] = g0;
            g[1*P_ + basep + ln] = g1v;
            g[2*P_ + basep + ln] = g2v;
            s0 += g0; s1 += g1v; s2 += g2v;
            s00 = fmaf(g0,g0,s00); s01 = fmaf(g0,g1v,s01); s02 = fmaf(g0,g2v,s02);
            s11 = fmaf(g1v,g1v,s11); s12 = fmaf(g1v,g2v,s12); s22 = fmaf(g2v,g2v,s22);
        }
    }
    // ---- point B
    {
        const int myi = select8(dB, lminB, listK[wv], ln);
        if (ln < 8) {
            const float4 q = xs4[myi];
            const float g0  = q.x - meB.x;
            const float g1v = q.y - meB.y;
            const float g2v = q.z - meB.z;
            const size_t basep = ((size_t)b*N_ + nB) * KNN;
            g[0*P_ + basep + ln] = g0;
            g[1*P_ + basep + ln] = g1v;
            g[2*P_ + basep + ln] = g2v;
            s0 += g0; s1 += g1v; s2 += g2v;
            s00 = fmaf(g0,g0,s00); s01 = fmaf(g0,g1v,s01); s02 = fmaf(g0,g2v,s02);
            s11 = fmaf(g1v,g1v,s11); s12 = fmaf(g1v,g2v,s12); s22 = fmaf(g2v,g2v,s22);
        }
    }

    if (ln < 8) {
        #pragma unroll
        for (int m = 1; m < 8; m <<= 1) {
            s0 += __shfl_xor(s0, m);  s1 += __shfl_xor(s1, m);  s2 += __shfl_xor(s2, m);
            s00 += __shfl_xor(s00, m); s01 += __shfl_xor(s01, m); s02 += __shfl_xor(s02, m);
            s11 += __shfl_xor(s11, m); s12 += __shfl_xor(s12, m); s22 += __shfl_xor(s22, m);
        }
        if (ln == 0) {
            spart[wv][0] = s0;  spart[wv][1] = s1;  spart[wv][2] = s2;
            spart[wv][3] = s00; spart[wv][4] = s01; spart[wv][5] = s02;
            spart[wv][6] = s11; spart[wv][7] = s12; spart[wv][8] = s22;
        }
    }
    __syncthreads();
    if (tid < 9) {
        float a = 0.f;
        #pragma unroll
        for (int w = 0; w < 16; ++w) a += spart[w][tid];
        kpart[tid*KBLKS + blockIdx.y*64 + blockIdx.x] = a;
    }
}

// ---------------------------------------------------------------------------
// Layer-1 BN stats from g moment partials (wave-parallel); emit W1f.
__global__ __launch_bounds__(1024) void finalize1_kernel(
    const float* __restrict__ kpart, const float* __restrict__ W1,
    const float* __restrict__ b1, const float* __restrict__ g1,
    const float* __restrict__ be1, float* __restrict__ ab)
{
    __shared__ double S9[9];
    const int tid = threadIdx.x;
    const int w = tid >> 6, l = tid & 63;
    if (w < 9) {
        double a = 0.0;
        #pragma unroll
        for (int i = 0; i < 16; ++i) a += (double)kpart[w*KBLKS + l + 64*i];
        #pragma unroll
        for (int m = 1; m < 64; m <<= 1) a += __shfl_xor(a, m);
        if (l == 0) S9[w] = a;
    }
    __syncthreads();
    if (tid < 128) {
        const int d = tid;
        const double inv = 1.0 / (double)P_;
        const double mu0 = S9[0]*inv, mu1 = S9[1]*inv, mu2 = S9[2]*inv;
        const double c00 = S9[3]*inv - mu0*mu0;
        const double c01 = S9[4]*inv - mu0*mu1;
        const double c02 = S9[5]*inv - mu0*mu2;
        const double c11 = S9[6]*inv - mu1*mu1;
        const double c12 = S9[7]*inv - mu1*mu2;
        const double c22 = S9[8]*inv - mu2*mu2;
        const double w0 = W1[d*3+0], w1 = W1[d*3+1], w2 = W1[d*3+2];
        const double mean = w0*mu0 + w1*mu1 + w2*mu2 + (double)b1[d];
        double var = w0*w0*c00 + w1*w1*c11 + w2*w2*c22
                   + 2.0*(w0*w1*c01 + w0*w2*c02 + w1*w2*c12);
        if (var < 0.0) var = 0.0;
        const double r = 1.0 / sqrt(var + 1e-5);
        const double alpha = (double)g1[d] * r;
        const double beta  = (double)be1[d] - mean*alpha;
        ab[AB_W1F + 4*d + 0] = (float)(alpha * w0);
        ab[AB_W1F + 4*d + 1] = (float)(alpha * w1);
        ab[AB_W1F + 4*d + 2] = (float)(alpha * w2);
        ab[AB_W1F + 4*d + 3] = (float)(alpha * (double)b1[d] + beta);
    }
}

// Per-block BN affine from banked stats (exact finalize23 f64 math).
__device__ __forceinline__ void bn_affine_block(
    const double* __restrict__ st, int soff, int d,
    const float* __restrict__ gg, const float* __restrict__ bee,
    float* __restrict__ al, float* __restrict__ el)
{
    double s1 = 0.0, s2 = 0.0;
    #pragma unroll
    for (int k = 0; k < NBANK; ++k) {
        s1 += st[soff + k*256 + d];
        s2 += st[soff + k*256 + 128 + d];
    }
    const double inv = 1.0 / (double)P_;
    const double mean = s1 * inv;
    double var = s2 * inv - mean*mean;
    if (var < 0.0) var = 0.0;
    const double r = 1.0 / sqrt(var + 1e-5);
    const double alpha = (double)gg[d] * r;
    al[d] = (float)alpha;
    el[d] = (float)((double)bee[d] - mean*alpha);
}

// ---------------------------------------------------------------------------
// MFMA conv (r17 proven): 512 thr = 8 waves; wave w owns d in [16w,16w+16).
// SRC 0: H from g via folded W1f (conv2).
// SRC 1: H = relu(a2*y2t+e2); a2/e2 computed per-block from stats (conv3).
// MODE 0: y2t via LDS transpose (stride 136) + stats.
// MODE 3: stats + per-point max/min packed bf16x2 -> ymm.
template<int SRC, int MODE>
__global__ __launch_bounds__(512) void conv_kernel(
    const float* __restrict__ gsrc, const unsigned short* __restrict__ ybsrc,
    const float* __restrict__ Wf, const float* __restrict__ ab,
    const float* __restrict__ bias, unsigned short* __restrict__ ybdst,
    unsigned* __restrict__ ymm, double* __restrict__ stats, int statoff,
    const float* __restrict__ gprev, const float* __restrict__ beprev)
{
    __shared__ __align__(16) short Hs[128*136];
    __shared__ float a2l[DIM], e2l[DIM];
    const int tid = threadIdx.x;          // 0..511
    const int p0g = blockIdx.x * 128;
    const int w  = tid >> 6;              // 0..7
    const int ln = tid & 63;
    const int lg = ln >> 4, lr = ln & 15;

    if constexpr (SRC == 1) {
        if (tid < DIM) bn_affine_block(stats, I_S2, tid, gprev, beprev, a2l, e2l);
        __syncthreads();
    }

    // A-frags: wave w covers d rows [16w, 16w+16)
    bf16x8 afrag[4];
    #pragma unroll
    for (int ks = 0; ks < 4; ++ks) {
        const float* wr = &Wf[(size_t)(16*w + lr)*DIM + (4*ks + lg)*8];
        const float4 a4 = *(const float4*)wr;
        const float4 b4 = *(const float4*)(wr + 4);
        bf16x8 f;
        f[0]=(short)f2bs(a4.x); f[1]=(short)f2bs(a4.y); f[2]=(short)f2bs(a4.z); f[3]=(short)f2bs(a4.w);
        f[4]=(short)f2bs(b4.x); f[5]=(short)f2bs(b4.y); f[6]=(short)f2bs(b4.z); f[7]=(short)f2bs(b4.w);
        afrag[ks] = f;
    }

    if constexpr (SRC == 0) {
        const int sp = tid & 127;
        const int ob = tid >> 7;          // 0..3
        const float gx = gsrc[0*P_ + p0g + sp];
        const float gy = gsrc[1*P_ + p0g + sp];
        const float gz = gsrc[2*P_ + p0g + sp];
        #pragma unroll
        for (int it = 0; it < 4; ++it) {
            const int o = ob + 4*it;
            bf16x8 hv;
            #pragma unroll
            for (int j = 0; j < 8; ++j) {
                const int c = 8*o + j;
                const float4 wf = *(const float4*)&ab[AB_W1F + 4*c];
                const float h = fmaxf(__fmaf_rn(wf.x, gx, __fmaf_rn(wf.y, gy, __fmaf_rn(wf.z, gz, wf.w))), 0.f);
                hv[j] = (short)f2bs(h);
            }
            *(bf16x8*)&Hs[sp*128 + ((o ^ (sp & 7)) * 8)] = hv;
        }
    } else {
        const int myoct = tid & 15;
        const float4 aLo = *(const float4*)&a2l[myoct*8];
        const float4 aHi = *(const float4*)&a2l[myoct*8 + 4];
        const float4 eLo = *(const float4*)&e2l[myoct*8];
        const float4 eHi = *(const float4*)&e2l[myoct*8 + 4];
        const float av[8] = {aLo.x,aLo.y,aLo.z,aLo.w,aHi.x,aHi.y,aHi.z,aHi.w};
        const float ev[8] = {eLo.x,eLo.y,eLo.z,eLo.w,eHi.x,eHi.y,eHi.z,eHi.w};
        #pragma unroll
        for (int it = 0; it < 4; ++it) {
            const int p = it*32 + (tid >> 4);
            const bf16x8 raw = *(const bf16x8*)&ybsrc[(size_t)(p0g + p)*128 + myoct*8];
            bf16x8 hv;
            #pragma unroll
            for (int j = 0; j < 8; ++j) {
                const float v = bs2f((unsigned short)raw[j]);
                hv[j] = (short)f2bs(fmaxf(__fmaf_rn(av[j], v, ev[j]), 0.f));
            }
            *(bf16x8*)&Hs[p*128 + ((myoct ^ (p & 7)) * 8)] = hv;
        }
    }
    __syncthreads();

    f32x4 acc[8];
    #pragma unroll
    for (int j = 0; j < 8; ++j) acc[j] = (f32x4){0.f, 0.f, 0.f, 0.f};

    #pragma unroll
    for (int ks = 0; ks < 4; ++ks) {
        #pragma unroll
        for (int pt = 0; pt < 8; ++pt) {
            const int p = 16*pt + lr;
            const bf16x8 bf = *(const bf16x8*)&Hs[p*128 + (((4*ks + lg) ^ (lr & 7)) * 8)];
            acc[pt] = __builtin_amdgcn_mfma_f32_16x16x32_bf16(afrag[ks], bf, acc[pt], 0, 0, 0);
        }
    }

    const int bank = blockIdx.x & (NBANK-1);
    #pragma unroll
    for (int r = 0; r < 4; ++r) {
        const int d = 16*w + 4*lg + r;
        const float bb = bias[d];
        float v[8];
        #pragma unroll
        for (int pt = 0; pt < 8; ++pt) v[pt] = acc[pt][r] + bb;

        float s1 = ((v[0]+v[1])+(v[2]+v[3])) + ((v[4]+v[5])+(v[6]+v[7]));
        float s2 = ((v[0]*v[0]+v[1]*v[1])+(v[2]*v[2]+v[3]*v[3]))
                 + ((v[4]*v[4]+v[5]*v[5])+(v[6]*v[6]+v[7]*v[7]));
        s1 += dppf<DPP_XOR1>(s1);  s2 += dppf<DPP_XOR1>(s2);
        s1 += dppf<DPP_XOR2>(s1);  s2 += dppf<DPP_XOR2>(s2);
        s1 += dppf<DPP_HALFM>(s1); s2 += dppf<DPP_HALFM>(s2);
        s1 += dppf<DPP_MIRROR>(s1); s2 += dppf<DPP_MIRROR>(s2);
        if (lr == 0) {
            atomAddD(&stats[statoff + bank*256 + d], (double)s1);
            atomAddD(&stats[statoff + bank*256 + 128 + d], (double)s2);
        }

        if constexpr (MODE == 3) {
            #pragma unroll
            for (int pt = 0; pt < 8; ++pt) {
                float mx = v[pt], mn = v[pt];
                mx = fmaxf(mx, dppf<DPP_XOR1>(mx));  mn = fminf(mn, dppf<DPP_XOR1>(mn));
                mx = fmaxf(mx, dppf<DPP_XOR2>(mx));  mn = fminf(mn, dppf<DPP_XOR2>(mn));
                mx = fmaxf(mx, dppf<DPP_HALFM>(mx)); mn = fminf(mn, dppf<DPP_HALFM>(mn));
                if ((lr & 7) == 0) {
                    const int slot = 2*pt + (lr >> 3);
                    ymm[((size_t)d*NBLK + blockIdx.x)*16 + slot] =
                        (unsigned)f2bs(mx) | ((unsigned)f2bs(mn) << 16);
                }
            }
        }
    }

    if constexpr (MODE == 0) {
        __syncthreads();
        const int d0 = 16*w + 4*lg;
        const float4 b4 = *(const float4*)&bias[d0];
        #pragma unroll
        for (int pt = 0; pt < 8; ++pt) {
            const int p = 16*pt + lr;
            bf16x4 pk;
            pk[0] = (short)f2bs(acc[pt][0] + b4.x);
            pk[1] = (short)f2bs(acc[pt][1] + b4.y);
            pk[2] = (short)f2bs(acc[pt][2] + b4.z);
            pk[3] = (short)f2bs(acc[pt][3] + b4.w);
            *(bf16x4*)&Hs[p*136 + d0] = pk;
        }
        __syncthreads();
        #pragma unroll
        for (int it = 0; it < 4; ++it) {
            const int f = it*512 + tid;
            const int row = f >> 4, ch = f & 15;
            const bf16x8 vv = *(const bf16x8*)&Hs[row*136 + ch*8];
            *(bf16x8*)&ybdst[(size_t)(p0g + row)*128 + ch*8] = vv;
        }
    }
}

// ---------------------------------------------------------------------------
// Epilogue: out[b,d,n] = relu(a3*(a3>=0 ? max_k : min_k) + e3); a3/e3
// computed per-block from stats3 (finalize3 folded in).
__global__ __launch_bounds__(256) void bn3max_kernel(
    const unsigned* __restrict__ ymm, const double* __restrict__ stats,
    const float* __restrict__ g3, const float* __restrict__ be3,
    float* __restrict__ out)
{
    __shared__ float a3l[DIM], e3l[DIM];
    const int tid = threadIdx.x;
    if (tid < DIM) bn_affine_block(stats, I_S3, tid, g3, be3, a3l, e3l);
    __syncthreads();

    const int idx = blockIdx.x*256 + tid;
    const int n = idx & (N_-1);
    const int d = (idx >> 11) & (DIM-1);
    const int b = idx >> 18;
    const int pt  = b*N_ + n;
    const int blk = pt >> 4;
    const int j   = pt & 15;
    const unsigned pk = ymm[((size_t)d*NBLK + blk)*16 + j];
    const float a = a3l[d], e = e3l[d];
    const float mx = bs2f((unsigned short)(pk & 0xFFFF));
    const float mn = bs2f((unsigned short)(pk >> 16));
    const float v = (a >= 0.f) ? mx : mn;
    out[idx] = fmaxf(__fmaf_rn(a, v, e), 0.f);
}

// ---------------------------------------------------------------------------
extern "C" void kernel_launch(void* const* d_in, const int* in_sizes, int n_in,
                              void* d_out, int out_size, void* d_ws, size_t ws_size,
                              hipStream_t stream) {
    (void)in_sizes; (void)n_in; (void)out_size; (void)ws_size;
    const float* x   = (const float*)d_in[0];
    const float* W1  = (const float*)d_in[1];
    const float* b1  = (const float*)d_in[2];
    const float* g1  = (const float*)d_in[3];
    const float* be1 = (const float*)d_in[4];
    const float* W2  = (const float*)d_in[5];
    const float* b2  = (const float*)d_in[6];
    const float* g2  = (const float*)d_in[7];
    const float* be2 = (const float*)d_in[8];
    const float* W3  = (const float*)d_in[9];
    const float* b3  = (const float*)d_in[10];
    const float* g3  = (const float*)d_in[11];
    const float* be3 = (const float*)d_in[12];

    float*  out = (float*)d_out;
    char*   ws  = (char*)d_ws;
    float*          g   = (float*)(ws + OFF_G);
    unsigned short* y2t = (unsigned short*)(ws + OFF_Y2B);
    double*         st  = (double*)(ws + OFF_STATS);
    float*          ab  = (float*)(ws + OFF_AB);
    float*          kp  = (float*)(ws + OFF_KPART);
    unsigned*       ymm = (unsigned*)(ws + OFF_YMM);

    knn_group_kernel<<<dim3(N_/32, B_), 1024, 0, stream>>>(x, g, kp, st);
    finalize1_kernel<<<1, 1024, 0, stream>>>(kp, W1, b1, g1, be1, ab);
    conv_kernel<0,0><<<NBLK, 512, 0, stream>>>(g, nullptr, W2, ab, b2, y2t, nullptr, st, I_S2, nullptr, nullptr);
    conv_kernel<1,3><<<NBLK, 512, 0, stream>>>(nullptr, y2t, W3, ab, b3, nullptr, ymm, st, I_S3, g2, be2);
    bn3max_kernel<<<(B_*DIM*N_)/256, 256, 0, stream>>>(ymm, st, g3, be3, out);
}

// Round 19
// 162.448 us; speedup vs baseline: 1.4090x; 1.4090x over previous
//
#include <hip/hip_runtime.h>
#include <hip/hip_bf16.h>
#include <math.h>

// ---------------------------------------------------------------------------
// FeatureNet (DGCNN edge-conv block), MI355X / gfx950, round 19.
//
// Round-19 = r17 kNN (proven 54.5us; r18's 2-points-per-wave spilled dA/dB
// to scratch -> 120us, reverted) + r18's launch folding (finalize2 -> conv3
// prologue, finalize3 -> bn3max prologue; 5 launches).
// ---------------------------------------------------------------------------

#define B_   16
#define N_   2048
#define KNN  8
#define DIM  128
#define P_   (B_*N_*KNN)   // 262144
#define CAP  128
#define NBLK 2048          // conv blocks (128 p each)
#define NKBLK 2048         // knn blocks (16 points each)

typedef __attribute__((ext_vector_type(8))) short bf16x8;
typedef __attribute__((ext_vector_type(4))) short bf16x4;
typedef __attribute__((ext_vector_type(4))) float f32x4;

// ws layout (bytes)
#define OFF_G     0ull
#define SZ_G      ((size_t)3*P_*4)
#define OFF_Y2B   (OFF_G + SZ_G)
#define SZ_Y2B    ((size_t)DIM*P_*2)           // 67,108,864  (y2t[p][c])
#define OFF_STATS (OFF_Y2B + SZ_Y2B)
#define N_STATS   4112
#define SZ_STATS  ((size_t)N_STATS*8)
#define OFF_AB    (OFF_STATS + SZ_STATS)
#define SZ_AB     4096ull
#define OFF_KPART (OFF_AB + SZ_AB)
#define SZ_KPART  ((size_t)9*NKBLK*4)
#define OFF_YMM   (OFF_KPART + SZ_KPART)
#define SZ_YMM    ((size_t)DIM*NBLK*16*4)      // packed u32 (max,min)

// stats (f64) indices
#define I_S2   16
#define I_S3   (16 + 8*256)
#define NBANK  8

// ab (float) layout
#define AB_W1F 0

// DPP ctrl codes (all source lanes valid)
#define DPP_XOR1   0xB1    // quad_perm [1,0,3,2]
#define DPP_XOR2   0x4E    // quad_perm [2,3,0,1]
#define DPP_HALFM  0x141   // row_half_mirror: lane ^ 7
#define DPP_MIRROR 0x140   // row_mirror: lane ^ 15

template<int C>
__device__ __forceinline__ float dppf(float v) {
    return __int_as_float(__builtin_amdgcn_update_dpp(
        __float_as_int(v), __float_as_int(v), C, 0xF, 0xF, false));
}

__device__ __forceinline__ void atomAddD(double* p, double v) {
    __hip_atomic_fetch_add(p, v, __ATOMIC_RELAXED, __HIP_MEMORY_SCOPE_AGENT);
}
__device__ __forceinline__ unsigned short f2bs(float f) {
    const unsigned b = __float_as_uint(f);
    return (unsigned short)((b + 0x7FFFu + ((b >> 16) & 1u)) >> 16);   // RNE
}
__device__ __forceinline__ float bs2f(unsigned short u) {
    return __uint_as_float(((unsigned)u) << 16);
}

// ---------------------------------------------------------------------------
// kNN + grouped offsets + layer-1 moment partials + stats zeroing (r17 proven).
__global__ __launch_bounds__(1024) void knn_group_kernel(
    const float* __restrict__ x, float* __restrict__ g,
    float* __restrict__ kpart, double* __restrict__ st)
{
    __shared__ __align__(16) float4 xs4[N_];
    __shared__ unsigned long long listK[16][CAP];
    __shared__ float spart[16][12];
    const int b   = blockIdx.y;
    const int tid = threadIdx.x;
    const int wv  = tid >> 6;
    const int ln  = tid & 63;
    const int n   = blockIdx.x * 16 + wv;
    const float* xb = x + (size_t)b * 3 * N_;

    if (blockIdx.x == 0 && blockIdx.y == 0)
        for (int i = tid; i < N_STATS; i += 1024) st[i] = 0.0;

    for (int i = tid; i < N_; i += 1024) {
        const float a0 = xb[i], a1 = xb[N_ + i], a2 = xb[2*N_ + i];
        const float sq = __fadd_rn(__fadd_rn(__fmul_rn(a0,a0), __fmul_rn(a1,a1)), __fmul_rn(a2,a2));
        xs4[i] = make_float4(a0, a1, a2, sq);
    }
    __syncthreads();

    const float4 me = xs4[n];
    const float xn0 = me.x, xn1 = me.y, xn2 = me.z, sqn = me.w;

    float dreg[32];
    float lmin = INFINITY;
    #pragma unroll
    for (int i = 0; i < 32; ++i) {
        const float4 q = xs4[ln + 64*i];
        dreg[i] = __fadd_rn(__fmaf_rn(-2.f, __fmaf_rn(xn2, q.z, __fmaf_rn(xn1, q.y, __fmul_rn(xn0, q.x))), sqn), q.w);
        lmin = fminf(lmin, dreg[i]);
    }

    float gm = lmin;
    gm = fminf(gm, __shfl_xor(gm, 1));
    gm = fminf(gm, __shfl_xor(gm, 2));
    gm = fminf(gm, __shfl_xor(gm, 4));
    float Bb = gm;
    Bb = fmaxf(Bb, __shfl_xor(Bb, 8));
    Bb = fmaxf(Bb, __shfl_xor(Bb, 16));
    Bb = fmaxf(Bb, __shfl_xor(Bb, 32));

    unsigned base = 0;
    #pragma unroll
    for (int i = 0; i < 32; ++i) {
        const bool pred = (dreg[i] <= Bb);
        const unsigned long long mk = __ballot(pred);
        if (pred) {
            const unsigned pos = base + (unsigned)__popcll(mk & ((1ull << ln) - 1ull));
            if (pos < CAP) {
                const unsigned u = __float_as_uint(dreg[i]);
                const unsigned od = u ^ ((unsigned)(((int)u) >> 31) | 0x80000000u);
                listK[wv][pos] = (((unsigned long long)od) << 32) | (unsigned)(ln + 64*i);
            }
        }
        base += (unsigned)__popcll(mk);
    }
    const int cnt = (base < CAP) ? (int)base : CAP;

    int myi = 0;
    if (cnt <= 64) {
        unsigned long long K = (ln < cnt) ? listK[wv][ln] : ~0ull;
        #pragma unroll
        for (int k = 2; k <= 64; k <<= 1) {
            #pragma unroll
            for (int j = k >> 1; j >= 1; j >>= 1) {
                const unsigned long long o = __shfl_xor(K, j);
                const bool takeMin = (((ln & j) == 0) == ((ln & k) == 0));
                const bool oLess = (o < K);
                if (takeMin ? oLess : !oLess) K = o;
            }
        }
        myi = (int)(unsigned)K;
    } else {
        unsigned long long K0 = (ln < cnt)      ? listK[wv][ln]      : ~0ull;
        unsigned long long K1 = (ln + 64 < cnt) ? listK[wv][ln + 64] : ~0ull;
        #pragma unroll
        for (int sel = 0; sel < 8; ++sel) {
            unsigned long long p = (K1 < K0) ? K1 : K0;
            #pragma unroll
            for (int m = 1; m < 64; m <<= 1) {
                const unsigned long long o = __shfl_xor(p, m);
                if (o < p) p = o;
            }
            if (ln == sel) myi = (int)(unsigned)p;
            if (K0 == p) K0 = ~0ull;
            if (K1 == p) K1 = ~0ull;
        }
    }

    if (ln < 8) {
        const float4 q = xs4[myi];
        const float g0  = q.x - xn0;
        const float g1v = q.y - xn1;
        const float g2v = q.z - xn2;
        const size_t basep = ((size_t)b*N_ + n) * KNN;
        g[0*P_ + basep + ln] = g0;
        g[1*P_ + basep + ln] = g1v;
        g[2*P_ + basep + ln] = g2v;
        float s0 = g0, s1 = g1v, s2 = g2v;
        float s00 = g0*g0, s01 = g0*g1v, s02 = g0*g2v;
        float s11 = g1v*g1v, s12 = g1v*g2v, s22 = g2v*g2v;
        #pragma unroll
        for (int m = 1; m < 8; m <<= 1) {
            s0 += __shfl_xor(s0, m);  s1 += __shfl_xor(s1, m);  s2 += __shfl_xor(s2, m);
            s00 += __shfl_xor(s00, m); s01 += __shfl_xor(s01, m); s02 += __shfl_xor(s02, m);
            s11 += __shfl_xor(s11, m); s12 += __shfl_xor(s12, m); s22 += __shfl_xor(s22, m);
        }
        if (ln == 0) {
            spart[wv][0] = s0;  spart[wv][1] = s1;  spart[wv][2] = s2;
            spart[wv][3] = s00; spart[wv][4] = s01; spart[wv][5] = s02;
            spart[wv][6] = s11; spart[wv][7] = s12; spart[wv][8] = s22;
        }
    }
    __syncthreads();
    if (tid < 9) {
        float a = 0.f;
        #pragma unroll
        for (int w = 0; w < 16; ++w) a += spart[w][tid];
        kpart[tid*NKBLK + blockIdx.y*128 + blockIdx.x] = a;
    }
}

// ---------------------------------------------------------------------------
// Layer-1 BN stats from g moment partials (wave-parallel); emit W1f.
__global__ __launch_bounds__(1024) void finalize1_kernel(
    const float* __restrict__ kpart, const float* __restrict__ W1,
    const float* __restrict__ b1, const float* __restrict__ g1,
    const float* __restrict__ be1, float* __restrict__ ab)
{
    __shared__ double S9[9];
    const int tid = threadIdx.x;
    const int w = tid >> 6, l = tid & 63;
    if (w < 9) {
        double a = 0.0;
        #pragma unroll
        for (int i = 0; i < 32; ++i) a += (double)kpart[w*NKBLK + l + 64*i];
        #pragma unroll
        for (int m = 1; m < 64; m <<= 1) a += __shfl_xor(a, m);
        if (l == 0) S9[w] = a;
    }
    __syncthreads();
    if (tid < 128) {
        const int d = tid;
        const double inv = 1.0 / (double)P_;
        const double mu0 = S9[0]*inv, mu1 = S9[1]*inv, mu2 = S9[2]*inv;
        const double c00 = S9[3]*inv - mu0*mu0;
        const double c01 = S9[4]*inv - mu0*mu1;
        const double c02 = S9[5]*inv - mu0*mu2;
        const double c11 = S9[6]*inv - mu1*mu1;
        const double c12 = S9[7]*inv - mu1*mu2;
        const double c22 = S9[8]*inv - mu2*mu2;
        const double w0 = W1[d*3+0], w1 = W1[d*3+1], w2 = W1[d*3+2];
        const double mean = w0*mu0 + w1*mu1 + w2*mu2 + (double)b1[d];
        double var = w0*w0*c00 + w1*w1*c11 + w2*w2*c22
                   + 2.0*(w0*w1*c01 + w0*w2*c02 + w1*w2*c12);
        if (var < 0.0) var = 0.0;
        const double r = 1.0 / sqrt(var + 1e-5);
        const double alpha = (double)g1[d] * r;
        const double beta  = (double)be1[d] - mean*alpha;
        ab[AB_W1F + 4*d + 0] = (float)(alpha * w0);
        ab[AB_W1F + 4*d + 1] = (float)(alpha * w1);
        ab[AB_W1F + 4*d + 2] = (float)(alpha * w2);
        ab[AB_W1F + 4*d + 3] = (float)(alpha * (double)b1[d] + beta);
    }
}

// Per-block BN affine from banked stats (exact finalize23 f64 math).
__device__ __forceinline__ void bn_affine_block(
    const double* __restrict__ st, int soff, int d,
    const float* __restrict__ gg, const float* __restrict__ bee,
    float* __restrict__ al, float* __restrict__ el)
{
    double s1 = 0.0, s2 = 0.0;
    #pragma unroll
    for (int k = 0; k < NBANK; ++k) {
        s1 += st[soff + k*256 + d];
        s2 += st[soff + k*256 + 128 + d];
    }
    const double inv = 1.0 / (double)P_;
    const double mean = s1 * inv;
    double var = s2 * inv - mean*mean;
    if (var < 0.0) var = 0.0;
    const double r = 1.0 / sqrt(var + 1e-5);
    const double alpha = (double)gg[d] * r;
    al[d] = (float)alpha;
    el[d] = (float)((double)bee[d] - mean*alpha);
}

// ---------------------------------------------------------------------------
// MFMA conv (r17 proven): 512 thr = 8 waves; wave w owns d in [16w,16w+16).
// SRC 0: H from g via folded W1f (conv2).
// SRC 1: H = relu(a2*y2t+e2); a2/e2 computed per-block from stats (conv3).
// MODE 0: y2t via LDS transpose (stride 136) + stats.
// MODE 3: stats + per-point max/min packed bf16x2 -> ymm.
template<int SRC, int MODE>
__global__ __launch_bounds__(512) void conv_kernel(
    const float* __restrict__ gsrc, const unsigned short* __restrict__ ybsrc,
    const float* __restrict__ Wf, const float* __restrict__ ab,
    const float* __restrict__ bias, unsigned short* __restrict__ ybdst,
    unsigned* __restrict__ ymm, double* __restrict__ stats, int statoff,
    const float* __restrict__ gprev, const float* __restrict__ beprev)
{
    __shared__ __align__(16) short Hs[128*136];
    __shared__ float a2l[DIM], e2l[DIM];
    const int tid = threadIdx.x;          // 0..511
    const int p0g = blockIdx.x * 128;
    const int w  = tid >> 6;              // 0..7
    const int ln = tid & 63;
    const int lg = ln >> 4, lr = ln & 15;

    if constexpr (SRC == 1) {
        if (tid < DIM) bn_affine_block(stats, I_S2, tid, gprev, beprev, a2l, e2l);
        __syncthreads();
    }

    // A-frags: wave w covers d rows [16w, 16w+16)
    bf16x8 afrag[4];
    #pragma unroll
    for (int ks = 0; ks < 4; ++ks) {
        const float* wr = &Wf[(size_t)(16*w + lr)*DIM + (4*ks + lg)*8];
        const float4 a4 = *(const float4*)wr;
        const float4 b4 = *(const float4*)(wr + 4);
        bf16x8 f;
        f[0]=(short)f2bs(a4.x); f[1]=(short)f2bs(a4.y); f[2]=(short)f2bs(a4.z); f[3]=(short)f2bs(a4.w);
        f[4]=(short)f2bs(b4.x); f[5]=(short)f2bs(b4.y); f[6]=(short)f2bs(b4.z); f[7]=(short)f2bs(b4.w);
        afrag[ks] = f;
    }

    if constexpr (SRC == 0) {
        const int sp = tid & 127;
        const int ob = tid >> 7;          // 0..3
        const float gx = gsrc[0*P_ + p0g + sp];
        const float gy = gsrc[1*P_ + p0g + sp];
        const float gz = gsrc[2*P_ + p0g + sp];
        #pragma unroll
        for (int it = 0; it < 4; ++it) {
            const int o = ob + 4*it;
            bf16x8 hv;
            #pragma unroll
            for (int j = 0; j < 8; ++j) {
                const int c = 8*o + j;
                const float4 wf = *(const float4*)&ab[AB_W1F + 4*c];
                const float h = fmaxf(__fmaf_rn(wf.x, gx, __fmaf_rn(wf.y, gy, __fmaf_rn(wf.z, gz, wf.w))), 0.f);
                hv[j] = (short)f2bs(h);
            }
            *(bf16x8*)&Hs[sp*128 + ((o ^ (sp & 7)) * 8)] = hv;
        }
    } else {
        const int myoct = tid & 15;
        const float4 aLo = *(const float4*)&a2l[myoct*8];
        const float4 aHi = *(const float4*)&a2l[myoct*8 + 4];
        const float4 eLo = *(const float4*)&e2l[myoct*8];
        const float4 eHi = *(const float4*)&e2l[myoct*8 + 4];
        const float av[8] = {aLo.x,aLo.y,aLo.z,aLo.w,aHi.x,aHi.y,aHi.z,aHi.w};
        const float ev[8] = {eLo.x,eLo.y,eLo.z,eLo.w,eHi.x,eHi.y,eHi.z,eHi.w};
        #pragma unroll
        for (int it = 0; it < 4; ++it) {
            const int p = it*32 + (tid >> 4);
            const bf16x8 raw = *(const bf16x8*)&ybsrc[(size_t)(p0g + p)*128 + myoct*8];
            bf16x8 hv;
            #pragma unroll
            for (int j = 0; j < 8; ++j) {
                const float v = bs2f((unsigned short)raw[j]);
                hv[j] = (short)f2bs(fmaxf(__fmaf_rn(av[j], v, ev[j]), 0.f));
            }
            *(bf16x8*)&Hs[p*128 + ((myoct ^ (p & 7)) * 8)] = hv;
        }
    }
    __syncthreads();

    f32x4 acc[8];
    #pragma unroll
    for (int j = 0; j < 8; ++j) acc[j] = (f32x4){0.f, 0.f, 0.f, 0.f};

    #pragma unroll
    for (int ks = 0; ks < 4; ++ks) {
        #pragma unroll
        for (int pt = 0; pt < 8; ++pt) {
            const int p = 16*pt + lr;
            const bf16x8 bf = *(const bf16x8*)&Hs[p*128 + (((4*ks + lg) ^ (lr & 7)) * 8)];
            acc[pt] = __builtin_amdgcn_mfma_f32_16x16x32_bf16(afrag[ks], bf, acc[pt], 0, 0, 0);
        }
    }

    const int bank = blockIdx.x & (NBANK-1);
    #pragma unroll
    for (int r = 0; r < 4; ++r) {
        const int d = 16*w + 4*lg + r;
        const float bb = bias[d];
        float v[8];
        #pragma unroll
        for (int pt = 0; pt < 8; ++pt) v[pt] = acc[pt][r] + bb;

        float s1 = ((v[0]+v[1])+(v[2]+v[3])) + ((v[4]+v[5])+(v[6]+v[7]));
        float s2 = ((v[0]*v[0]+v[1]*v[1])+(v[2]*v[2]+v[3]*v[3]))
                 + ((v[4]*v[4]+v[5]*v[5])+(v[6]*v[6]+v[7]*v[7]));
        s1 += dppf<DPP_XOR1>(s1);  s2 += dppf<DPP_XOR1>(s2);
        s1 += dppf<DPP_XOR2>(s1);  s2 += dppf<DPP_XOR2>(s2);
        s1 += dppf<DPP_HALFM>(s1); s2 += dppf<DPP_HALFM>(s2);
        s1 += dppf<DPP_MIRROR>(s1); s2 += dppf<DPP_MIRROR>(s2);
        if (lr == 0) {
            atomAddD(&stats[statoff + bank*256 + d], (double)s1);
            atomAddD(&stats[statoff + bank*256 + 128 + d], (double)s2);
        }

        if constexpr (MODE == 3) {
            #pragma unroll
            for (int pt = 0; pt < 8; ++pt) {
                float mx = v[pt], mn = v[pt];
                mx = fmaxf(mx, dppf<DPP_XOR1>(mx));  mn = fminf(mn, dppf<DPP_XOR1>(mn));
                mx = fmaxf(mx, dppf<DPP_XOR2>(mx));  mn = fminf(mn, dppf<DPP_XOR2>(mn));
                mx = fmaxf(mx, dppf<DPP_HALFM>(mx)); mn = fminf(mn, dppf<DPP_HALFM>(mn));
                if ((lr & 7) == 0) {
                    const int slot = 2*pt + (lr >> 3);
                    ymm[((size_t)d*NBLK + blockIdx.x)*16 + slot] =
                        (unsigned)f2bs(mx) | ((unsigned)f2bs(mn) << 16);
                }
            }
        }
    }

    if constexpr (MODE == 0) {
        __syncthreads();
        const int d0 = 16*w + 4*lg;
        const float4 b4 = *(const float4*)&bias[d0];
        #pragma unroll
        for (int pt = 0; pt < 8; ++pt) {
            const int p = 16*pt + lr;
            bf16x4 pk;
            pk[0] = (short)f2bs(acc[pt][0] + b4.x);
            pk[1] = (short)f2bs(acc[pt][1] + b4.y);
            pk[2] = (short)f2bs(acc[pt][2] + b4.z);
            pk[3] = (short)f2bs(acc[pt][3] + b4.w);
            *(bf16x4*)&Hs[p*136 + d0] = pk;
        }
        __syncthreads();
        #pragma unroll
        for (int it = 0; it < 4; ++it) {
            const int f = it*512 + tid;
            const int row = f >> 4, ch = f & 15;
            const bf16x8 vv = *(const bf16x8*)&Hs[row*136 + ch*8];
            *(bf16x8*)&ybdst[(size_t)(p0g + row)*128 + ch*8] = vv;
        }
    }
}

// ---------------------------------------------------------------------------
// Epilogue: out[b,d,n] = relu(a3*(a3>=0 ? max_k : min_k) + e3); a3/e3
// computed per-block from stats3 (finalize3 folded in).
__global__ __launch_bounds__(256) void bn3max_kernel(
    const unsigned* __restrict__ ymm, const double* __restrict__ stats,
    const float* __restrict__ g3, const float* __restrict__ be3,
    float* __restrict__ out)
{
    __shared__ float a3l[DIM], e3l[DIM];
    const int tid = threadIdx.x;
    if (tid < DIM) bn_affine_block(stats, I_S3, tid, g3, be3, a3l, e3l);
    __syncthreads();

    const int idx = blockIdx.x*256 + tid;
    const int n = idx & (N_-1);
    const int d = (idx >> 11) & (DIM-1);
    const int b = idx >> 18;
    const int pt  = b*N_ + n;
    const int blk = pt >> 4;
    const int j   = pt & 15;
    const unsigned pk = ymm[((size_t)d*NBLK + blk)*16 + j];
    const float a = a3l[d], e = e3l[d];
    const float mx = bs2f((unsigned short)(pk & 0xFFFF));
    const float mn = bs2f((unsigned short)(pk >> 16));
    const float v = (a >= 0.f) ? mx : mn;
    out[idx] = fmaxf(__fmaf_rn(a, v, e), 0.f);
}

// ---------------------------------------------------------------------------
extern "C" void kernel_launch(void* const* d_in, const int* in_sizes, int n_in,
                              void* d_out, int out_size, void* d_ws, size_t ws_size,
                              hipStream_t stream) {
    (void)in_sizes; (void)n_in; (void)out_size; (void)ws_size;
    const float* x   = (const float*)d_in[0];
    const float* W1  = (const float*)d_in[1];
    const float* b1  = (const float*)d_in[2];
    const float* g1  = (const float*)d_in[3];
    const float* be1 = (const float*)d_in[4];
    const float* W2  = (const float*)d_in[5];
    const float* b2  = (const float*)d_in[6];
    const float* g2  = (const float*)d_in[7];
    const float* be2 = (const float*)d_in[8];
    const float* W3  = (const float*)d_in[9];
    const float* b3  = (const float*)d_in[10];
    const float* g3  = (const float*)d_in[11];
    const float* be3 = (const float*)d_in[12];

    float*  out = (float*)d_out;
    char*   ws  = (char*)d_ws;
    float*          g   = (float*)(ws + OFF_G);
    unsigned short* y2t = (unsigned short*)(ws + OFF_Y2B);
    double*         st  = (double*)(ws + OFF_STATS);
    float*          ab  = (float*)(ws + OFF_AB);
    float*          kp  = (float*)(ws + OFF_KPART);
    unsigned*       ymm = (unsigned*)(ws + OFF_YMM);

    knn_group_kernel<<<dim3(128, B_), 1024, 0, stream>>>(x, g, kp, st);
    finalize1_kernel<<<1, 1024, 0, stream>>>(kp, W1, b1, g1, be1, ab);
    conv_kernel<0,0><<<NBLK, 512, 0, stream>>>(g, nullptr, W2, ab, b2, y2t, nullptr, st, I_S2, nullptr, nullptr);
    conv_kernel<1,3><<<NBLK, 512, 0, stream>>>(nullptr, y2t, W3, ab, b3, nullptr, ymm, st, I_S3, g2, be2);
    bn3max_kernel<<<(B_*DIM*N_)/256, 256, 0, stream>>>(ymm, st, g3, be3, out);
}

// Round 20
// 153.563 us; speedup vs baseline: 1.4905x; 1.0579x over previous
//
#include <hip/hip_runtime.h>
#include <hip/hip_bf16.h>
#include <math.h>

// ---------------------------------------------------------------------------
// FeatureNet (DGCNN edge-conv block), MI355X / gfx950, round 20.
//
// Round-20 = r17 proven pipeline (153.5us) + SELECTIVE launch folding:
//  * finalize2 folded into conv3 prologue (2048 blocks -> cheap, r19-proven).
//  * finalize3 + bn3max kept as r17 (r19 folded it into 16384 bn3max blocks
//    -> 16384x redundant f64 affine, +9us regression; reverted).
// 6 launches.
// ---------------------------------------------------------------------------

#define B_   16
#define N_   2048
#define KNN  8
#define DIM  128
#define P_   (B_*N_*KNN)   // 262144
#define CAP  128
#define NBLK 2048          // conv blocks (128 p each)
#define NKBLK 2048         // knn blocks (16 points each)

typedef __attribute__((ext_vector_type(8))) short bf16x8;
typedef __attribute__((ext_vector_type(4))) short bf16x4;
typedef __attribute__((ext_vector_type(4))) float f32x4;

// ws layout (bytes)
#define OFF_G     0ull
#define SZ_G      ((size_t)3*P_*4)
#define OFF_Y2B   (OFF_G + SZ_G)
#define SZ_Y2B    ((size_t)DIM*P_*2)           // 67,108,864  (y2t[p][c])
#define OFF_STATS (OFF_Y2B + SZ_Y2B)
#define N_STATS   4112
#define SZ_STATS  ((size_t)N_STATS*8)
#define OFF_AB    (OFF_STATS + SZ_STATS)
#define SZ_AB     4096ull
#define OFF_KPART (OFF_AB + SZ_AB)
#define SZ_KPART  ((size_t)9*NKBLK*4)
#define OFF_YMM   (OFF_KPART + SZ_KPART)
#define SZ_YMM    ((size_t)DIM*NBLK*16*4)      // packed u32 (max,min)

// stats (f64) indices
#define I_S2   16
#define I_S3   (16 + 8*256)
#define NBANK  8

// ab (float) layout
#define AB_W1F 0
#define AB_A3  768
#define AB_E3  896

// DPP ctrl codes (all source lanes valid)
#define DPP_XOR1   0xB1    // quad_perm [1,0,3,2]
#define DPP_XOR2   0x4E    // quad_perm [2,3,0,1]
#define DPP_HALFM  0x141   // row_half_mirror: lane ^ 7
#define DPP_MIRROR 0x140   // row_mirror: lane ^ 15

template<int C>
__device__ __forceinline__ float dppf(float v) {
    return __int_as_float(__builtin_amdgcn_update_dpp(
        __float_as_int(v), __float_as_int(v), C, 0xF, 0xF, false));
}

__device__ __forceinline__ void atomAddD(double* p, double v) {
    __hip_atomic_fetch_add(p, v, __ATOMIC_RELAXED, __HIP_MEMORY_SCOPE_AGENT);
}
__device__ __forceinline__ unsigned short f2bs(float f) {
    const unsigned b = __float_as_uint(f);
    return (unsigned short)((b + 0x7FFFu + ((b >> 16) & 1u)) >> 16);   // RNE
}
__device__ __forceinline__ float bs2f(unsigned short u) {
    return __uint_as_float(((unsigned)u) << 16);
}

// ---------------------------------------------------------------------------
// kNN + grouped offsets + layer-1 moment partials + stats zeroing (r17 proven).
__global__ __launch_bounds__(1024) void knn_group_kernel(
    const float* __restrict__ x, float* __restrict__ g,
    float* __restrict__ kpart, double* __restrict__ st)
{
    __shared__ __align__(16) float4 xs4[N_];
    __shared__ unsigned long long listK[16][CAP];
    __shared__ float spart[16][12];
    const int b   = blockIdx.y;
    const int tid = threadIdx.x;
    const int wv  = tid >> 6;
    const int ln  = tid & 63;
    const int n   = blockIdx.x * 16 + wv;
    const float* xb = x + (size_t)b * 3 * N_;

    if (blockIdx.x == 0 && blockIdx.y == 0)
        for (int i = tid; i < N_STATS; i += 1024) st[i] = 0.0;

    for (int i = tid; i < N_; i += 1024) {
        const float a0 = xb[i], a1 = xb[N_ + i], a2 = xb[2*N_ + i];
        const float sq = __fadd_rn(__fadd_rn(__fmul_rn(a0,a0), __fmul_rn(a1,a1)), __fmul_rn(a2,a2));
        xs4[i] = make_float4(a0, a1, a2, sq);
    }
    __syncthreads();

    const float4 me = xs4[n];
    const float xn0 = me.x, xn1 = me.y, xn2 = me.z, sqn = me.w;

    float dreg[32];
    float lmin = INFINITY;
    #pragma unroll
    for (int i = 0; i < 32; ++i) {
        const float4 q = xs4[ln + 64*i];
        dreg[i] = __fadd_rn(__fmaf_rn(-2.f, __fmaf_rn(xn2, q.z, __fmaf_rn(xn1, q.y, __fmul_rn(xn0, q.x))), sqn), q.w);
        lmin = fminf(lmin, dreg[i]);
    }

    float gm = lmin;
    gm = fminf(gm, __shfl_xor(gm, 1));
    gm = fminf(gm, __shfl_xor(gm, 2));
    gm = fminf(gm, __shfl_xor(gm, 4));
    float Bb = gm;
    Bb = fmaxf(Bb, __shfl_xor(Bb, 8));
    Bb = fmaxf(Bb, __shfl_xor(Bb, 16));
    Bb = fmaxf(Bb, __shfl_xor(Bb, 32));

    unsigned base = 0;
    #pragma unroll
    for (int i = 0; i < 32; ++i) {
        const bool pred = (dreg[i] <= Bb);
        const unsigned long long mk = __ballot(pred);
        if (pred) {
            const unsigned pos = base + (unsigned)__popcll(mk & ((1ull << ln) - 1ull));
            if (pos < CAP) {
                const unsigned u = __float_as_uint(dreg[i]);
                const unsigned od = u ^ ((unsigned)(((int)u) >> 31) | 0x80000000u);
                listK[wv][pos] = (((unsigned long long)od) << 32) | (unsigned)(ln + 64*i);
            }
        }
        base += (unsigned)__popcll(mk);
    }
    const int cnt = (base < CAP) ? (int)base : CAP;

    int myi = 0;
    if (cnt <= 64) {
        unsigned long long K = (ln < cnt) ? listK[wv][ln] : ~0ull;
        #pragma unroll
        for (int k = 2; k <= 64; k <<= 1) {
            #pragma unroll
            for (int j = k >> 1; j >= 1; j >>= 1) {
                const unsigned long long o = __shfl_xor(K, j);
                const bool takeMin = (((ln & j) == 0) == ((ln & k) == 0));
                const bool oLess = (o < K);
                if (takeMin ? oLess : !oLess) K = o;
            }
        }
        myi = (int)(unsigned)K;
    } else {
        unsigned long long K0 = (ln < cnt)      ? listK[wv][ln]      : ~0ull;
        unsigned long long K1 = (ln + 64 < cnt) ? listK[wv][ln + 64] : ~0ull;
        #pragma unroll
        for (int sel = 0; sel < 8; ++sel) {
            unsigned long long p = (K1 < K0) ? K1 : K0;
            #pragma unroll
            for (int m = 1; m < 64; m <<= 1) {
                const unsigned long long o = __shfl_xor(p, m);
                if (o < p) p = o;
            }
            if (ln == sel) myi = (int)(unsigned)p;
            if (K0 == p) K0 = ~0ull;
            if (K1 == p) K1 = ~0ull;
        }
    }

    if (ln < 8) {
        const float4 q = xs4[myi];
        const float g0  = q.x - xn0;
        const float g1v = q.y - xn1;
        const float g2v = q.z - xn2;
        const size_t basep = ((size_t)b*N_ + n) * KNN;
        g[0*P_ + basep + ln] = g0;
        g[1*P_ + basep + ln] = g1v;
        g[2*P_ + basep + ln] = g2v;
        float s0 = g0, s1 = g1v, s2 = g2v;
        float s00 = g0*g0, s01 = g0*g1v, s02 = g0*g2v;
        float s11 = g1v*g1v, s12 = g1v*g2v, s22 = g2v*g2v;
        #pragma unroll
        for (int m = 1; m < 8; m <<= 1) {
            s0 += __shfl_xor(s0, m);  s1 += __shfl_xor(s1, m);  s2 += __shfl_xor(s2, m);
            s00 += __shfl_xor(s00, m); s01 += __shfl_xor(s01, m); s02 += __shfl_xor(s02, m);
            s11 += __shfl_xor(s11, m); s12 += __shfl_xor(s12, m); s22 += __shfl_xor(s22, m);
        }
        if (ln == 0) {
            spart[wv][0] = s0;  spart[wv][1] = s1;  spart[wv][2] = s2;
            spart[wv][3] = s00; spart[wv][4] = s01; spart[wv][5] = s02;
            spart[wv][6] = s11; spart[wv][7] = s12; spart[wv][8] = s22;
        }
    }
    __syncthreads();
    if (tid < 9) {
        float a = 0.f;
        #pragma unroll
        for (int w = 0; w < 16; ++w) a += spart[w][tid];
        kpart[tid*NKBLK + blockIdx.y*128 + blockIdx.x] = a;
    }
}

// ---------------------------------------------------------------------------
// Layer-1 BN stats from g moment partials (wave-parallel); emit W1f.
__global__ __launch_bounds__(1024) void finalize1_kernel(
    const float* __restrict__ kpart, const float* __restrict__ W1,
    const float* __restrict__ b1, const float* __restrict__ g1,
    const float* __restrict__ be1, float* __restrict__ ab)
{
    __shared__ double S9[9];
    const int tid = threadIdx.x;
    const int w = tid >> 6, l = tid & 63;
    if (w < 9) {
        double a = 0.0;
        #pragma unroll
        for (int i = 0; i < 32; ++i) a += (double)kpart[w*NKBLK + l + 64*i];
        #pragma unroll
        for (int m = 1; m < 64; m <<= 1) a += __shfl_xor(a, m);
        if (l == 0) S9[w] = a;
    }
    __syncthreads();
    if (tid < 128) {
        const int d = tid;
        const double inv = 1.0 / (double)P_;
        const double mu0 = S9[0]*inv, mu1 = S9[1]*inv, mu2 = S9[2]*inv;
        const double c00 = S9[3]*inv - mu0*mu0;
        const double c01 = S9[4]*inv - mu0*mu1;
        const double c02 = S9[5]*inv - mu0*mu2;
        const double c11 = S9[6]*inv - mu1*mu1;
        const double c12 = S9[7]*inv - mu1*mu2;
        const double c22 = S9[8]*inv - mu2*mu2;
        const double w0 = W1[d*3+0], w1 = W1[d*3+1], w2 = W1[d*3+2];
        const double mean = w0*mu0 + w1*mu1 + w2*mu2 + (double)b1[d];
        double var = w0*w0*c00 + w1*w1*c11 + w2*w2*c22
                   + 2.0*(w0*w1*c01 + w0*w2*c02 + w1*w2*c12);
        if (var < 0.0) var = 0.0;
        const double r = 1.0 / sqrt(var + 1e-5);
        const double alpha = (double)g1[d] * r;
        const double beta  = (double)be1[d] - mean*alpha;
        ab[AB_W1F + 4*d + 0] = (float)(alpha * w0);
        ab[AB_W1F + 4*d + 1] = (float)(alpha * w1);
        ab[AB_W1F + 4*d + 2] = (float)(alpha * w2);
        ab[AB_W1F + 4*d + 3] = (float)(alpha * (double)b1[d] + beta);
    }
}

// finalize3 (1 block): banked stats -> a3/e3 into ab.
__global__ void finalize3_kernel(
    const double* __restrict__ st,
    const float* __restrict__ g3, const float* __restrict__ be3,
    float* __restrict__ ab)
{
    const int d = threadIdx.x;
    if (d >= DIM) return;
    double s1 = 0.0, s2 = 0.0;
    #pragma unroll
    for (int k = 0; k < NBANK; ++k) {
        s1 += st[I_S3 + k*256 + d];
        s2 += st[I_S3 + k*256 + 128 + d];
    }
    const double inv = 1.0 / (double)P_;
    const double mean = s1 * inv;
    double var = s2 * inv - mean*mean;
    if (var < 0.0) var = 0.0;
    const double r = 1.0 / sqrt(var + 1e-5);
    const double alpha = (double)g3[d] * r;
    ab[AB_A3 + d] = (float)alpha;
    ab[AB_E3 + d] = (float)((double)be3[d] - mean*alpha);
}

// Per-block BN affine from banked stats (exact f64 math; conv3 prologue).
__device__ __forceinline__ void bn_affine_block(
    const double* __restrict__ st, int soff, int d,
    const float* __restrict__ gg, const float* __restrict__ bee,
    float* __restrict__ al, float* __restrict__ el)
{
    double s1 = 0.0, s2 = 0.0;
    #pragma unroll
    for (int k = 0; k < NBANK; ++k) {
        s1 += st[soff + k*256 + d];
        s2 += st[soff + k*256 + 128 + d];
    }
    const double inv = 1.0 / (double)P_;
    const double mean = s1 * inv;
    double var = s2 * inv - mean*mean;
    if (var < 0.0) var = 0.0;
    const double r = 1.0 / sqrt(var + 1e-5);
    const double alpha = (double)gg[d] * r;
    al[d] = (float)alpha;
    el[d] = (float)((double)bee[d] - mean*alpha);
}

// ---------------------------------------------------------------------------
// MFMA conv (r17 proven): 512 thr = 8 waves; wave w owns d in [16w,16w+16).
// SRC 0: H from g via folded W1f (conv2).
// SRC 1: H = relu(a2*y2t+e2); a2/e2 per-block from stats (conv3, r19-proven).
// MODE 0: y2t via LDS transpose (stride 136) + stats.
// MODE 3: stats + per-point max/min packed bf16x2 -> ymm.
template<int SRC, int MODE>
__global__ __launch_bounds__(512) void conv_kernel(
    const float* __restrict__ gsrc, const unsigned short* __restrict__ ybsrc,
    const float* __restrict__ Wf, const float* __restrict__ ab,
    const float* __restrict__ bias, unsigned short* __restrict__ ybdst,
    unsigned* __restrict__ ymm, double* __restrict__ stats, int statoff,
    const float* __restrict__ gprev, const float* __restrict__ beprev)
{
    __shared__ __align__(16) short Hs[128*136];
    __shared__ float a2l[DIM], e2l[DIM];
    const int tid = threadIdx.x;          // 0..511
    const int p0g = blockIdx.x * 128;
    const int w  = tid >> 6;              // 0..7
    const int ln = tid & 63;
    const int lg = ln >> 4, lr = ln & 15;

    if constexpr (SRC == 1) {
        if (tid < DIM) bn_affine_block(stats, I_S2, tid, gprev, beprev, a2l, e2l);
        __syncthreads();
    }

    bf16x8 afrag[4];
    #pragma unroll
    for (int ks = 0; ks < 4; ++ks) {
        const float* wr = &Wf[(size_t)(16*w + lr)*DIM + (4*ks + lg)*8];
        const float4 a4 = *(const float4*)wr;
        const float4 b4 = *(const float4*)(wr + 4);
        bf16x8 f;
        f[0]=(short)f2bs(a4.x); f[1]=(short)f2bs(a4.y); f[2]=(short)f2bs(a4.z); f[3]=(short)f2bs(a4.w);
        f[4]=(short)f2bs(b4.x); f[5]=(short)f2bs(b4.y); f[6]=(short)f2bs(b4.z); f[7]=(short)f2bs(b4.w);
        afrag[ks] = f;
    }

    if constexpr (SRC == 0) {
        const int sp = tid & 127;
        const int ob = tid >> 7;          // 0..3
        const float gx = gsrc[0*P_ + p0g + sp];
        const float gy = gsrc[1*P_ + p0g + sp];
        const float gz = gsrc[2*P_ + p0g + sp];
        #pragma unroll
        for (int it = 0; it < 4; ++it) {
            const int o = ob + 4*it;
            bf16x8 hv;
            #pragma unroll
            for (int j = 0; j < 8; ++j) {
                const int c = 8*o + j;
                const float4 wf = *(const float4*)&ab[AB_W1F + 4*c];
                const float h = fmaxf(__fmaf_rn(wf.x, gx, __fmaf_rn(wf.y, gy, __fmaf_rn(wf.z, gz, wf.w))), 0.f);
                hv[j] = (short)f2bs(h);
            }
            *(bf16x8*)&Hs[sp*128 + ((o ^ (sp & 7)) * 8)] = hv;
        }
    } else {
        const int myoct = tid & 15;
        const float4 aLo = *(const float4*)&a2l[myoct*8];
        const float4 aHi = *(const float4*)&a2l[myoct*8 + 4];
        const float4 eLo = *(const float4*)&e2l[myoct*8];
        const float4 eHi = *(const float4*)&e2l[myoct*8 + 4];
        const float av[8] = {aLo.x,aLo.y,aLo.z,aLo.w,aHi.x,aHi.y,aHi.z,aHi.w};
        const float ev[8] = {eLo.x,eLo.y,eLo.z,eLo.w,eHi.x,eHi.y,eHi.z,eHi.w};
        #pragma unroll
        for (int it = 0; it < 4; ++it) {
            const int p = it*32 + (tid >> 4);
            const bf16x8 raw = *(const bf16x8*)&ybsrc[(size_t)(p0g + p)*128 + myoct*8];
            bf16x8 hv;
            #pragma unroll
            for (int j = 0; j < 8; ++j) {
                const float v = bs2f((unsigned short)raw[j]);
                hv[j] = (short)f2bs(fmaxf(__fmaf_rn(av[j], v, ev[j]), 0.f));
            }
            *(bf16x8*)&Hs[p*128 + ((myoct ^ (p & 7)) * 8)] = hv;
        }
    }
    __syncthreads();

    f32x4 acc[8];
    #pragma unroll
    for (int j = 0; j < 8; ++j) acc[j] = (f32x4){0.f, 0.f, 0.f, 0.f};

    #pragma unroll
    for (int ks = 0; ks < 4; ++ks) {
        #pragma unroll
        for (int pt = 0; pt < 8; ++pt) {
            const int p = 16*pt + lr;
            const bf16x8 bf = *(const bf16x8*)&Hs[p*128 + (((4*ks + lg) ^ (lr & 7)) * 8)];
            acc[pt] = __builtin_amdgcn_mfma_f32_16x16x32_bf16(afrag[ks], bf, acc[pt], 0, 0, 0);
        }
    }

    const int bank = blockIdx.x & (NBANK-1);
    #pragma unroll
    for (int r = 0; r < 4; ++r) {
        const int d = 16*w + 4*lg + r;
        const float bb = bias[d];
        float v[8];
        #pragma unroll
        for (int pt = 0; pt < 8; ++pt) v[pt] = acc[pt][r] + bb;

        float s1 = ((v[0]+v[1])+(v[2]+v[3])) + ((v[4]+v[5])+(v[6]+v[7]));
        float s2 = ((v[0]*v[0]+v[1]*v[1])+(v[2]*v[2]+v[3]*v[3]))
                 + ((v[4]*v[4]+v[5]*v[5])+(v[6]*v[6]+v[7]*v[7]));
        s1 += dppf<DPP_XOR1>(s1);  s2 += dppf<DPP_XOR1>(s2);
        s1 += dppf<DPP_XOR2>(s1);  s2 += dppf<DPP_XOR2>(s2);
        s1 += dppf<DPP_HALFM>(s1); s2 += dppf<DPP_HALFM>(s2);
        s1 += dppf<DPP_MIRROR>(s1); s2 += dppf<DPP_MIRROR>(s2);
        if (lr == 0) {
            atomAddD(&stats[statoff + bank*256 + d], (double)s1);
            atomAddD(&stats[statoff + bank*256 + 128 + d], (double)s2);
        }

        if constexpr (MODE == 3) {
            #pragma unroll
            for (int pt = 0; pt < 8; ++pt) {
                float mx = v[pt], mn = v[pt];
                mx = fmaxf(mx, dppf<DPP_XOR1>(mx));  mn = fminf(mn, dppf<DPP_XOR1>(mn));
                mx = fmaxf(mx, dppf<DPP_XOR2>(mx));  mn = fminf(mn, dppf<DPP_XOR2>(mn));
                mx = fmaxf(mx, dppf<DPP_HALFM>(mx)); mn = fminf(mn, dppf<DPP_HALFM>(mn));
                if ((lr & 7) == 0) {
                    const int slot = 2*pt + (lr >> 3);
                    ymm[((size_t)d*NBLK + blockIdx.x)*16 + slot] =
                        (unsigned)f2bs(mx) | ((unsigned)f2bs(mn) << 16);
                }
            }
        }
    }

    if constexpr (MODE == 0) {
        __syncthreads();
        const int d0 = 16*w + 4*lg;
        const float4 b4 = *(const float4*)&bias[d0];
        #pragma unroll
        for (int pt = 0; pt < 8; ++pt) {
            const int p = 16*pt + lr;
            bf16x4 pk;
            pk[0] = (short)f2bs(acc[pt][0] + b4.x);
            pk[1] = (short)f2bs(acc[pt][1] + b4.y);
            pk[2] = (short)f2bs(acc[pt][2] + b4.z);
            pk[3] = (short)f2bs(acc[pt][3] + b4.w);
            *(bf16x4*)&Hs[p*136 + d0] = pk;
        }
        __syncthreads();
        #pragma unroll
        for (int it = 0; it < 4; ++it) {
            const int f = it*512 + tid;
            const int row = f >> 4, ch = f & 15;
            const bf16x8 vv = *(const bf16x8*)&Hs[row*136 + ch*8];
            *(bf16x8*)&ybdst[(size_t)(p0g + row)*128 + ch*8] = vv;
        }
    }
}

// ---------------------------------------------------------------------------
// Epilogue (r17 proven, no prologue): out = relu(a3*(a3>=0?max:min)+e3).
__global__ __launch_bounds__(256) void bn3max_kernel(
    const unsigned* __restrict__ ymm, const float* __restrict__ ab, float* __restrict__ out)
{
    const int idx = blockIdx.x*256 + threadIdx.x;
    const int n = idx & (N_-1);
    const int d = (idx >> 11) & (DIM-1);
    const int b = idx >> 18;
    const int pt  = b*N_ + n;
    const int blk = pt >> 4;
    const int j   = pt & 15;
    const unsigned pk = ymm[((size_t)d*NBLK + blk)*16 + j];
    const float a = ab[AB_A3 + d], e = ab[AB_E3 + d];
    const float mx = bs2f((unsigned short)(pk & 0xFFFF));
    const float mn = bs2f((unsigned short)(pk >> 16));
    const float v = (a >= 0.f) ? mx : mn;
    out[idx] = fmaxf(__fmaf_rn(a, v, e), 0.f);
}

// ---------------------------------------------------------------------------
extern "C" void kernel_launch(void* const* d_in, const int* in_sizes, int n_in,
                              void* d_out, int out_size, void* d_ws, size_t ws_size,
                              hipStream_t stream) {
    (void)in_sizes; (void)n_in; (void)out_size; (void)ws_size;
    const float* x   = (const float*)d_in[0];
    const float* W1  = (const float*)d_in[1];
    const float* b1  = (const float*)d_in[2];
    const float* g1  = (const float*)d_in[3];
    const float* be1 = (const float*)d_in[4];
    const float* W2  = (const float*)d_in[5];
    const float* b2  = (const float*)d_in[6];
    const float* g2  = (const float*)d_in[7];
    const float* be2 = (const float*)d_in[8];
    const float* W3  = (const float*)d_in[9];
    const float* b3  = (const float*)d_in[10];
    const float* g3  = (const float*)d_in[11];
    const float* be3 = (const float*)d_in[12];

    float*  out = (float*)d_out;
    char*   ws  = (char*)d_ws;
    float*          g   = (float*)(ws + OFF_G);
    unsigned short* y2t = (unsigned short*)(ws + OFF_Y2B);
    double*         st  = (double*)(ws + OFF_STATS);
    float*          ab  = (float*)(ws + OFF_AB);
    float*          kp  = (float*)(ws + OFF_KPART);
    unsigned*       ymm = (unsigned*)(ws + OFF_YMM);

    knn_group_kernel<<<dim3(128, B_), 1024, 0, stream>>>(x, g, kp, st);
    finalize1_kernel<<<1, 1024, 0, stream>>>(kp, W1, b1, g1, be1, ab);
    conv_kernel<0,0><<<NBLK, 512, 0, stream>>>(g, nullptr, W2, ab, b2, y2t, nullptr, st, I_S2, nullptr, nullptr);
    conv_kernel<1,3><<<NBLK, 512, 0, stream>>>(nullptr, y2t, W3, ab, b3, nullptr, ymm, st, I_S3, g2, be2);
    finalize3_kernel<<<1, 128, 0, stream>>>(st, g3, be3, ab);
    bn3max_kernel<<<(B_*DIM*N_)/256, 256, 0, stream>>>(ymm, ab, out);
}